// Round 1
// baseline (1196.020 us; speedup 1.0000x reference)
//
#include <hip/hip_runtime.h>

typedef unsigned short u16;
typedef unsigned int   u32;
typedef __attribute__((ext_vector_type(4))) float f32x4;
typedef __attribute__((ext_vector_type(8))) u16   u16x8;
typedef __attribute__((ext_vector_type(4))) u16   u16x4;

// ---------------- helpers ----------------
__device__ __forceinline__ u16 f2bf(float x) {
  u32 u = __builtin_bit_cast(u32, x);
  u = (u + 0x7fffu + ((u >> 16) & 1u)) >> 16;
  return (u16)u;
}
__device__ __forceinline__ float bf2f(u16 h) {
  return __builtin_bit_cast(float, (u32)h << 16);
}
__device__ __forceinline__ float fast_sig(float x) { return 1.f / (1.f + __expf(-x)); }
__device__ __forceinline__ float fast_tanh(float x) {
  float e = __expf(2.f * x);
  return 1.f - 2.f / (e + 1.f);
}

// MFMA via inline asm (tied C/D accumulator) to avoid builtin-signature ambiguity.
__device__ __forceinline__ f32x4 mfma_bf16(u16x8 a, u16x8 b, f32x4 c) {
  asm volatile("v_mfma_f32_16x16x32_bf16 %0, %1, %2, %0" : "+v"(c) : "v"(a), "v"(b));
  return c;
}

__device__ __forceinline__ void gload_lds16(const void* g, void* l) {
  __builtin_amdgcn_global_load_lds(
      (__attribute__((address_space(1))) u32*)g,
      (__attribute__((address_space(3))) u32*)l, 16, 0, 0);
}

// ---------------- prep kernels ----------------
__global__ __launch_bounds__(256) void k_f32_to_bf16(const float* __restrict__ s,
                                                     u16* __restrict__ d, int n) {
  int i = (blockIdx.x * 256 + threadIdx.x) * 4;
  if (i + 4 <= n) {
    f32x4 v = *(const f32x4*)(s + i);
    u16x4 o;
    o.x = f2bf(v.x); o.y = f2bf(v.y); o.z = f2bf(v.z); o.w = f2bf(v.w);
    *(u16x4*)(d + i) = o;
  } else {
    for (; i < n; ++i) d[i] = f2bf(s[i]);
  }
}

// W_cat = [W_ih | W_hh] rows of length 1280, bf16
__global__ __launch_bounds__(256) void k_build_wcat(const float* __restrict__ Wih,
                                                    const float* __restrict__ Whh,
                                                    u16* __restrict__ d) {
  int i = blockIdx.x * 256 + threadIdx.x;  // [0, 2048*1280)
  int r = i / 1280, c = i - r * 1280;
  float v = (c < 768) ? Wih[r * 768 + c] : Whh[r * 512 + (c - 768)];
  d[i] = f2bf(v);
}

// W_gen padded to 6656 rows (rows >= 6624 zero)
__global__ __launch_bounds__(256) void k_build_wgen(const float* __restrict__ Wg,
                                                    u16* __restrict__ d) {
  int i = blockIdx.x * 256 + threadIdx.x;  // [0, 6656*512)
  int r = i >> 9;
  d[i] = f2bf(r < 6624 ? Wg[i] : 0.f);
}

__global__ __launch_bounds__(256) void k_bias_cat(const float* __restrict__ a,
                                                  const float* __restrict__ b,
                                                  float* __restrict__ d) {
  int i = blockIdx.x * 256 + threadIdx.x;  // 2048
  d[i] = a[i] + b[i];
}

// ---------------- GEMM: C[M,N] = A[M,K] * B[N,K]^T (+bias), bf16 in, f32 acc ----------------
// OUT_MODE: 0 = f32, 1 = f32 + bias, 2 = bf16 (no bias)
template <int BM, int BN, int WM, int WN, int OUT_MODE>
__global__ __launch_bounds__(256) void gemm_bt(const u16* __restrict__ A, int lda,
                                               const u16* __restrict__ B, int ldb,
                                               const float* __restrict__ bias,
                                               float* __restrict__ Cf, u16* __restrict__ Cb,
                                               int ldc, int Nreal, int K) {
  static_assert((BM / WM) * (BN / WN) == 4, "4 waves");
  constexpr int FM = WM / 16, FN = WN / 16;
  constexpr int NWC = BN / WN;
  constexpr int CHA = (BM * 4) / 256, CHB = (BN * 4) / 256;
  __shared__ __align__(16) u16 sA[BM * 32];
  __shared__ __align__(16) u16 sB[BN * 32];
  const int tid = threadIdx.x;
  const int lane = tid & 63, wave = tid >> 6;
  const int wr = wave / NWC, wc = wave % NWC;
  const int l15 = lane & 15, lhi = lane >> 4;
  const int m0 = blockIdx.y * BM, n0 = blockIdx.x * BN;

  f32x4 acc[FM][FN];
#pragma unroll
  for (int i = 0; i < FM; ++i)
#pragma unroll
    for (int j = 0; j < FN; ++j) acc[i][j] = 0.f;

  for (int k0 = 0; k0 < K; k0 += 32) {
    __syncthreads();  // protect LDS from previous iteration readers
#pragma unroll
    for (int j = 0; j < CHA; ++j) {
      int idx = j * 256 + tid;
      int row = idx >> 2, cc = idx & 3;
      int c = cc ^ ((row >> 1) & 3);  // bank-spread swizzle (both-sides)
      gload_lds16(A + (size_t)(m0 + row) * lda + (k0 + c * 8), sA + idx * 8);
    }
#pragma unroll
    for (int j = 0; j < CHB; ++j) {
      int idx = j * 256 + tid;
      int row = idx >> 2, cc = idx & 3;
      int c = cc ^ ((row >> 1) & 3);
      gload_lds16(B + (size_t)(n0 + row) * ldb + (k0 + c * 8), sB + idx * 8);
    }
    __syncthreads();  // compiler drains vmcnt before barrier

    u16x8 av[FM], bv[FN];
#pragma unroll
    for (int mi = 0; mi < FM; ++mi) {
      int row = wr * WM + mi * 16 + l15;
      int ch = row * 4 + (lhi ^ ((row >> 1) & 3));
      av[mi] = *(const u16x8*)(sA + ch * 8);
    }
#pragma unroll
    for (int ni = 0; ni < FN; ++ni) {
      int row = wc * WN + ni * 16 + l15;
      int ch = row * 4 + (lhi ^ ((row >> 1) & 3));
      bv[ni] = *(const u16x8*)(sB + ch * 8);
    }
#pragma unroll
    for (int mi = 0; mi < FM; ++mi)
#pragma unroll
      for (int ni = 0; ni < FN; ++ni) acc[mi][ni] = mfma_bf16(av[mi], bv[ni], acc[mi][ni]);
  }

  asm volatile("s_nop 7\ns_nop 7\ns_nop 7");  // MFMA->VALU hazard guard (asm is opaque)

#pragma unroll
  for (int mi = 0; mi < FM; ++mi) {
#pragma unroll
    for (int ni = 0; ni < FN; ++ni) {
      int col = n0 + wc * WN + ni * 16 + l15;
      if (col < Nreal) {
        float bvv = (OUT_MODE == 1) ? bias[col] : 0.f;
#pragma unroll
        for (int r = 0; r < 4; ++r) {
          int row = m0 + wr * WM + mi * 16 + lhi * 4 + r;
          float v = acc[mi][ni][r] + bvv;
          if (OUT_MODE == 2)
            Cb[(size_t)row * ldc + col] = f2bf(v);
          else
            Cf[(size_t)row * ldc + col] = v;
        }
      }
    }
  }
}

// ---------------- fused attention step ----------------
// e[b,t] = sum_h tanh(Hproj[b,t,h] + hp[b,h]) * w_score[h]; alpha = softmax_t(e);
// ctx[b,d] = sum_t alpha[t] * batch_H[b,t,d]; writes ctx (bf16) and ce (bf16) into Acat.
__global__ __launch_bounds__(256) void fused_attn(const u16* __restrict__ Hproj,
                                                  const float* __restrict__ hp,
                                                  const float* __restrict__ wsc,
                                                  const u16* __restrict__ bh,
                                                  const u16* __restrict__ embb,
                                                  const int* __restrict__ text, int step,
                                                  u16* __restrict__ Acat) {
  const int b = blockIdx.x, tid = threadIdx.x;
  __shared__ float es[64];
  const int hc = (tid & 15) << 5;
  const float* hpp = hp + b * 512 + hc;
  const float* wp = wsc + hc;
#pragma unroll
  for (int tg = 0; tg < 4; ++tg) {
    int t = tg * 16 + (tid >> 4);
    const u16* hr = Hproj + (b * 64 + t) * 512 + hc;
    float s = 0.f;
#pragma unroll
    for (int jo = 0; jo < 32; jo += 8) {
      u16x8 hv = *(const u16x8*)(hr + jo);
#pragma unroll
      for (int j = 0; j < 8; ++j) {
        float x = bf2f(hv[j]) + hpp[jo + j];
        s += fast_tanh(x) * wp[jo + j];
      }
    }
#pragma unroll
    for (int off = 8; off; off >>= 1) s += __shfl_xor(s, off, 16);
    if ((tid & 15) == 0) es[t] = s;
  }
  __syncthreads();
  if (tid < 64) {
    float v = es[tid];
    float m = v;
#pragma unroll
    for (int o = 32; o; o >>= 1) m = fmaxf(m, __shfl_xor(m, o, 64));
    float p = __expf(v - m);
    float su = p;
#pragma unroll
    for (int o = 32; o; o >>= 1) su += __shfl_xor(su, o, 64);
    es[tid] = p / su;
  }
  __syncthreads();
  const u16* base = bh + b * 32768 + tid * 2;
  float c0 = 0.f, c1 = 0.f;
#pragma unroll 8
  for (int t = 0; t < 64; ++t) {
    u32 w = *(const u32*)(base + t * 512);
    float a = es[t];
    c0 = fmaf(a, bf2f((u16)(w & 0xffffu)), c0);
    c1 = fmaf(a, bf2f((u16)(w >> 16)), c1);
  }
  u32 pk = (u32)f2bf(c0) | ((u32)f2bf(c1) << 16);
  *(u32*)(Acat + b * 1280 + tid * 2) = pk;
  int ci = text[b * 26 + step];
  Acat[b * 1280 + 512 + tid] = embb[ci * 256 + tid];
}

// ---------------- LSTM pointwise ----------------
__global__ __launch_bounds__(256) void lstm_cell(const float* __restrict__ gates,
                                                 float* __restrict__ cst,
                                                 u16* __restrict__ Acat,
                                                 u16* __restrict__ hsb, int step) {
  int idx = blockIdx.x * 256 + threadIdx.x;  // 256*512
  int b = idx >> 9, j = idx & 511;
  const float* g = gates + b * 2048;
  float iv = fast_sig(g[j]);
  float fv = fast_sig(g[512 + j]);
  float gv = fast_tanh(g[1024 + j]);
  float ov = fast_sig(g[1536 + j]);
  float cn = fv * cst[idx] + iv * gv;
  cst[idx] = cn;
  float h = ov * fast_tanh(cn);
  u16 hb = f2bf(h);
  Acat[b * 1280 + 768 + j] = hb;
  hsb[(b * 26 + step) * 512 + j] = hb;
}

// ---------------- launch ----------------
extern "C" void kernel_launch(void* const* d_in, const int* in_sizes, int n_in,
                              void* d_out, int out_size, void* d_ws, size_t ws_size,
                              hipStream_t stream) {
  const float* batch_H = (const float*)d_in[0];
  const int*   text    = (const int*)d_in[1];
  const float* W_i2h   = (const float*)d_in[2];
  const float* W_h2h   = (const float*)d_in[3];
  const float* b_h2h   = (const float*)d_in[4];
  const float* w_score = (const float*)d_in[5];
  const float* W_ih    = (const float*)d_in[6];
  const float* W_hh    = (const float*)d_in[7];
  const float* b_ih    = (const float*)d_in[8];
  const float* b_hh    = (const float*)d_in[9];
  const float* emb     = (const float*)d_in[10];
  const float* W_gen   = (const float*)d_in[11];
  const float* b_gen   = (const float*)d_in[12];
  float* out = (float*)d_out;

  // Big bf16 scratch lives at the front of d_out (fully overwritten by final GEMM,
  // which only reads hsb/Wgen). Everything else in d_ws (~25 MB).
  u16* bHb   = (u16*)d_out;          // 8,388,608 u16 = 16 MB
  u16* Hproj = bHb + 8388608;        // 8,388,608 u16 = 16 MB (out is 176 MB)

  char* w = (char*)d_ws;
  auto alloc = [&](size_t bytes) {
    char* p = w;
    w += (bytes + 255) & ~(size_t)255;
    return p;
  };
  u16*   Wi2hb   = (u16*)alloc(512ull * 512 * 2);
  u16*   Wh2hb   = (u16*)alloc(512ull * 512 * 2);
  u16*   Wcatb   = (u16*)alloc(2048ull * 1280 * 2);
  u16*   Wgenb   = (u16*)alloc(6656ull * 512 * 2);
  u16*   embb    = (u16*)alloc(6624ull * 256 * 2);
  float* biascat = (float*)alloc(2048ull * 4);
  u16*   Acat    = (u16*)alloc(256ull * 1280 * 2);  // [ctx(512) | ce(256) | h(512)]
  float* hp      = (float*)alloc(256ull * 512 * 4);
  float* gates   = (float*)alloc(256ull * 2048 * 4);
  float* cst     = (float*)alloc(256ull * 512 * 4);
  u16*   hsb     = (u16*)alloc(6656ull * 512 * 2);

  hipMemsetAsync(Acat, 0, 256ull * 1280 * 2, stream);  // h0 = 0 (ctx/ce overwritten per step)
  hipMemsetAsync(cst, 0, 256ull * 512 * 4, stream);    // c0 = 0

  k_f32_to_bf16<<<8192, 256, 0, stream>>>(batch_H, bHb, 8388608);
  k_f32_to_bf16<<<256, 256, 0, stream>>>(W_i2h, Wi2hb, 262144);
  k_f32_to_bf16<<<256, 256, 0, stream>>>(W_h2h, Wh2hb, 262144);
  k_f32_to_bf16<<<1656, 256, 0, stream>>>(emb, embb, 1695744);
  k_build_wcat<<<10240, 256, 0, stream>>>(W_ih, W_hh, Wcatb);
  k_build_wgen<<<13312, 256, 0, stream>>>(W_gen, Wgenb);
  k_bias_cat<<<8, 256, 0, stream>>>(b_ih, b_hh, biascat);

  // Hproj = batch_H @ W_i2h^T  -> bf16
  gemm_bt<128, 128, 64, 64, 2><<<dim3(4, 128), 256, 0, stream>>>(
      bHb, 512, Wi2hb, 512, nullptr, nullptr, Hproj, 512, 512, 512);

  for (int s = 0; s < 26; ++s) {
    // hp = h @ W_h2h^T + b_h2h   (h = Acat[:,768:1280], step s-1)
    gemm_bt<64, 64, 32, 32, 1><<<dim3(8, 4), 256, 0, stream>>>(
        Acat + 768, 1280, Wh2hb, 512, b_h2h, hp, nullptr, 512, 512, 512);
    // attention + context + ce gather -> Acat[:, 0:768]
    fused_attn<<<256, 256, 0, stream>>>(Hproj, hp, w_score, bHb, embb, text, s, Acat);
    // gates = [ctx|ce|h] @ [W_ih|W_hh]^T + (b_ih + b_hh)
    gemm_bt<64, 64, 32, 32, 1><<<dim3(32, 4), 256, 0, stream>>>(
        Acat, 1280, Wcatb, 1280, biascat, gates, nullptr, 2048, 2048, 1280);
    // LSTM cell, writes h (bf16) into Acat h-slice and hsb row (b*26+s)
    lstm_cell<<<512, 256, 0, stream>>>(gates, cst, Acat, hsb, s);
  }

  // probs = hs @ W_gen^T + b_gen -> f32 out (M=6656, N=6624 with guard, K=512)
  gemm_bt<128, 128, 64, 64, 1><<<dim3(52, 52), 256, 0, stream>>>(
      hsb, 512, Wgenb, 512, b_gen, out, nullptr, 6624, 6624, 512);

  (void)in_sizes; (void)n_in; (void)out_size; (void)ws_size;
}